// Round 14
// baseline (116.227 us; speedup 1.0000x reference)
//
#include <hip/hip_runtime.h>
#include <math.h>

// SimpleVQ: B=32, H=1, L=4096, D=64, S=512
#define NB 32
#define NL 4096
#define ND 64
#define NS 512
#define NTOK (NB*NL)          // 131072

// output layout (flat f32, return order)
#define OFF_Q 0
#define OFF_Z (NTOK*ND)
#define OFF_LC (OFF_Z + NTOK)
#define OFF_E (OFF_LC + 1)

typedef __attribute__((ext_vector_type(8))) short short8;
typedef __attribute__((ext_vector_type(4))) float f32x4;
typedef unsigned int u32;
typedef unsigned short u16;
typedef unsigned long long u64;

#define TOKS 256              // tokens per block
#define TPB 512               // 8 waves; 2 N-tiles (32 tokens) per wave
#define NBLK (NTOK / TOKS)    // 512 blocks
#define SLOTS 16              // candidate slots per token
#define EPS_H 1e-3f           // >= 2x 3-pass bf16-split h-error bound (proven r5-r12)

// round-to-nearest-even f32 -> bf16 bits
__device__ __forceinline__ u32 f2bf_rne(float x) {
    u32 u = __float_as_uint(x);
    return (u + 0x7fffu + ((u >> 16) & 1u)) >> 16;
}

__device__ __forceinline__ void upd_key(u64& best, float dist, int code) {
    u32 u = __float_as_uint(dist);
    u ^= (u >> 31) ? 0xFFFFFFFFu : 0x80000000u;   // monotone f32 -> u32
    u64 k = ((u64)u << 32) | (u32)code;
    if (k < best) best = k;
}

// exact reference distance: byte-identical chain to rounds 2-13
__device__ __forceinline__ float dist_code(const float* __restrict__ cb,
                                           const float* __restrict__ cc,
                                           const float4* vf, float vv, int code) {
    const float4* cs = (const float4*)(cb + (size_t)code * ND);
    float d0 = 0.f, d1 = 0.f, d2 = 0.f, d3 = 0.f;
    #pragma unroll
    for (int i = 0; i < 16; ++i) {
        float4 cv = cs[i];
        d0 = fmaf(cv.x, vf[i].x, d0);
        d1 = fmaf(cv.y, vf[i].y, d1);
        d2 = fmaf(cv.z, vf[i].z, d2);
        d3 = fmaf(cv.w, vf[i].w, d3);
    }
    float dot = (d0 + d1) + (d2 + d3);
    return (vv - 2.0f * dot) + cc[code];
}

// ---------------------------------------------------------------------------
// Kernel 1: codebook. cb f32 (linear), cc f32, LINEAR bf16 hi/lo arrays
// (no swizzle needed -- A-fragments are read straight from L1/L2).
// ---------------------------------------------------------------------------
__global__ void cb_kernel(float* __restrict__ cb, float* __restrict__ cc,
                          u16* __restrict__ cbh, u16* __restrict__ cbl) {
    int s = blockIdx.x;        // 0..511
    int d = threadIdx.x;       // 0..63
    int j = (d < 32) ? d : (d - 32);
    double e = -(double)(2 * j) / 64.0;
    double invlam = pow(100000.0, e);
    double pre = (double)s * invlam;
    float val = (float)((d < 32) ? sin(pre) : cos(pre));

    float sq = val * val;
    #pragma unroll
    for (int off = 32; off > 0; off >>= 1) sq += __shfl_xor(sq, off);
    float mean = sq * (1.0f / 64.0f);
    float scale = (1.0f / sqrtf(mean + 1e-6f)) * 0.35355339059327379f;
    float c = val * scale;
    cb[s * ND + d] = c;

    float c2 = c * c;
    #pragma unroll
    for (int off = 32; off > 0; off >>= 1) c2 += __shfl_xor(c2, off);
    if (d == 0) cc[s] = c2;

    u32 hb = f2bf_rne(c);
    float hf = __uint_as_float(hb << 16);
    u32 lb = f2bf_rne(c - hf);
    cbh[s * ND + d] = (u16)hb;
    cbl[s * ND + d] = (u16)lb;
}

// ---------------------------------------------------------------------------
// Kernel 2 (FUSED): 512 blocks x 512 threads (8 waves x 32 tokens).
// NO LDS codebook, NO staging, 2 barriers total:
//  P0: B-frags (bf16 hi/lo, 2 N-tiles/wave); zero counters; barrier.
//  P1: 8 chunks of 64 codes, barrier-free. A-fragments loaded directly from
//      global cbh/cbl (chunk working set 16 KB -> L1-hot; codebook 128 KB
//      L2-resident). 3-pass MFMA (h = dot - cc/2) -> per-chunk max +
//      eps-rescan -> slots (each wave writes only its own tokens).
//  P2: barrier; exact f32 rescore (identical dist chain), packed-key min
//      (first-min tie rule), 2 threads/token; overflow -> exact full scan.
//  P3: z / errs2 / partial / coalesced quantized gather-write.
// ---------------------------------------------------------------------------
__launch_bounds__(TPB, 2)
__global__ void fused_kernel(const float* __restrict__ vecs,
                             const float* __restrict__ mask,
                             const float* __restrict__ cb,
                             const float* __restrict__ cc,
                             const u16* __restrict__ cbh,
                             const u16* __restrict__ cbl,
                             float* __restrict__ outq,
                             float* __restrict__ outz,
                             float* __restrict__ oute,
                             float* __restrict__ partial) {
    __shared__ u16 slots[TOKS * SLOTS];         // 8 KB
    __shared__ u32 cnt_l[TOKS];                 // 1 KB
    __shared__ int z_l[TOKS];                   // 1 KB
    __shared__ float wsum[TPB / 64];

    const int tid = threadIdx.x;
    const int grp = blockIdx.x;      // 0..511
    const int w = tid >> 6;          // wave 0..7
    const int lane = tid & 63;
    const int c16 = lane & 15;
    const int h = lane >> 4;

    // ---- P0: B fragments (hi/lo), wave's 32 tokens (2 N-tiles) ----
    // B[k][col]: col = c16 (token), k = kk*32 + h*8 + e
    if (tid < TOKS) cnt_l[tid] = 0;
    short8 bh[2][2], bl[2][2];
    const int tokbase = grp * TOKS + w * 32;
    #pragma unroll
    for (int nt = 0; nt < 2; ++nt) {
        const float* vp = vecs + (size_t)(tokbase + nt * 16 + c16) * ND;
        #pragma unroll
        for (int kk = 0; kk < 2; ++kk) {
            const float4* p = (const float4*)(vp + kk * 32 + h * 8);
            float4 t0 = p[0], t1 = p[1];
            float x[8] = {t0.x, t0.y, t0.z, t0.w, t1.x, t1.y, t1.z, t1.w};
            short8 H, L;
            #pragma unroll
            for (int e2 = 0; e2 < 8; ++e2) {
                u32 hb = f2bf_rne(x[e2]);
                float hf = __uint_as_float(hb << 16);
                u32 lb = f2bf_rne(x[e2] - hf);
                H[e2] = (short)hb; L[e2] = (short)lb;
            }
            bh[nt][kk] = H; bl[nt][kk] = L;
        }
    }
    __syncthreads();                 // barrier #1

    // ---- P1: 8 chunks of 64 codes, barrier-free, A from L1/L2 ----
    for (int c = 0; c < 8; ++c) {
        f32x4 acc[4][2];             // [mt][nt]
        #pragma unroll
        for (int mt = 0; mt < 4; ++mt) {
            int cr = c * 64 + mt * 16 + h * 4;
            const float4 cv = *(const float4*)(cc + cr);   // L1/L2-hot
            f32x4 ini;
            ini[0] = -0.5f * cv.x;
            ini[1] = -0.5f * cv.y;
            ini[2] = -0.5f * cv.z;
            ini[3] = -0.5f * cv.w;
            acc[mt][0] = ini;
            acc[mt][1] = ini;
        }
        // A[row][k]: row = code (c16), k = kk*32 + h*8 + e  (linear layout)
        #pragma unroll
        for (int mt = 0; mt < 4; ++mt) {
            int code = c * 64 + mt * 16 + c16;
            const u16* rH = cbh + (size_t)code * ND;
            const u16* rL = cbl + (size_t)code * ND;
            short8 ah[2], al[2];
            #pragma unroll
            for (int kk = 0; kk < 2; ++kk) {
                ah[kk] = *(const short8*)(rH + kk * 32 + h * 8);
                al[kk] = *(const short8*)(rL + kk * 32 + h * 8);
            }
            #pragma unroll
            for (int nt = 0; nt < 2; ++nt) {
                #pragma unroll
                for (int kk = 0; kk < 2; ++kk) {
                    acc[mt][nt] = __builtin_amdgcn_mfma_f32_16x16x32_bf16(ah[kk], bh[nt][kk], acc[mt][nt], 0, 0, 0);
                    acc[mt][nt] = __builtin_amdgcn_mfma_f32_16x16x32_bf16(ah[kk], bl[nt][kk], acc[mt][nt], 0, 0, 0);
                    acc[mt][nt] = __builtin_amdgcn_mfma_f32_16x16x32_bf16(al[kk], bh[nt][kk], acc[mt][nt], 0, 0, 0);
                }
            }
        }
        // epilogue: per-token chunk max + eps-rescan -> candidate append
        #pragma unroll
        for (int nt = 0; nt < 2; ++nt) {
            float m = acc[0][nt][0];
            #pragma unroll
            for (int mt = 0; mt < 4; ++mt) {
                m = fmaxf(m, fmaxf(fmaxf(acc[mt][nt][0], acc[mt][nt][1]),
                                   fmaxf(acc[mt][nt][2], acc[mt][nt][3])));
            }
            m = fmaxf(m, __shfl_xor(m, 16));
            m = fmaxf(m, __shfl_xor(m, 32));
            float thr = m - EPS_H;
            int tl = w * 32 + nt * 16 + c16;
            #pragma unroll
            for (int mt = 0; mt < 4; ++mt) {
                #pragma unroll
                for (int r = 0; r < 4; ++r) {
                    float v = acc[mt][nt][r];
                    if (v >= thr) {
                        u32 pos = atomicAdd(&cnt_l[tl], 1u);
                        if (pos < (u32)SLOTS)
                            slots[tl * SLOTS + pos] = (u16)(c * 64 + mt * 16 + h * 4 + r);
                    }
                }
            }
        }
    }
    __syncthreads();                 // barrier #2

    // ---- P2: exact rescore, 2 threads/token ----
    const int p = tid >> 1;          // token-local 0..255
    const int half = tid & 1;
    const int tok = grp * TOKS + p;

    float4 vf[16];
    {
        const float4* vr = (const float4*)(vecs + (size_t)tok * ND);
        #pragma unroll
        for (int g = 0; g < 16; ++g) vf[g] = vr[g];
    }
    float vv;
    {
        float a0 = 0.f, a1 = 0.f, a2 = 0.f, a3 = 0.f;
        #pragma unroll
        for (int i = 0; i < 16; ++i) {
            a0 = fmaf(vf[i].x, vf[i].x, a0);
            a1 = fmaf(vf[i].y, vf[i].y, a1);
            a2 = fmaf(vf[i].z, vf[i].z, a2);
            a3 = fmaf(vf[i].w, vf[i].w, a3);
        }
        vv = (a0 + a1) + (a2 + a3);
    }

    u64 best = 0xFFFFFFFFFFFFFFFFull;
    u32 cntraw = cnt_l[p];
    if (cntraw > (u32)SLOTS) {
        // overflow fallback: exact full scan (deterministic trigger & result)
        for (int code = half; code < NS; code += 2)
            upd_key(best, dist_code(cb, cc, vf, vv, code), code);
    } else {
        for (u32 j2 = half; j2 < cntraw; j2 += 2) {
            int code = (int)slots[p * SLOTS + j2];
            upd_key(best, dist_code(cb, cc, vf, vv, code), code);
        }
    }
    {
        u64 o = __shfl_xor(best, 1);
        if (o < best) best = o;
    }

    float contrib = 0.0f;
    if (half == 0) {
        int zi = (int)(best & 0xFFFFFFFFu);
        u32 du = (u32)(best >> 32);
        du ^= (du >> 31) ? 0x80000000u : 0xFFFFFFFFu;
        float dmin = __uint_as_float(du);
        float err = fmaxf(dmin, 0.0f);
        outz[tok] = (float)zi;
        oute[tok] = err;
        z_l[p] = zi;
        contrib = mask[tok] * err;
    }
    #pragma unroll
    for (int off = 32; off > 0; off >>= 1) contrib += __shfl_xor(contrib, off);
    if (lane == 0) wsum[w] = contrib;
    __syncthreads();
    if (tid == 0) {
        float t = 0.f;
        #pragma unroll
        for (int i = 0; i < TPB / 64; ++i) t += wsum[i];
        partial[grp] = t;
    }

    // ---- P3: coalesced quantized gather-write ----
    const float4* cb4 = (const float4*)cb;
    float4* qo = (float4*)(outq + (size_t)grp * TOKS * ND);
    #pragma unroll
    for (int i = 0; i < 8; ++i) {
        int gidx = i * TPB + tid;      // 4096 f4
        int t2 = gidx >> 4;
        int sub = gidx & 15;
        qo[gidx] = cb4[(size_t)z_l[t2] * 16 + sub];
    }
}

// ---------------------------------------------------------------------------
// Kernel 3: sum 512 partials; l_commit = sum / (B*L)
// ---------------------------------------------------------------------------
__global__ void fin_kernel(const float* __restrict__ partial, float* __restrict__ outl) {
    int t = threadIdx.x;                 // 512
    float x = partial[t];
    #pragma unroll
    for (int off = 32; off > 0; off >>= 1) x += __shfl_xor(x, off);
    __shared__ float ws[8];
    if ((t & 63) == 0) ws[t >> 6] = x;
    __syncthreads();
    if (t == 0) {
        float s = 0.f;
        #pragma unroll
        for (int i = 0; i < 8; ++i) s += ws[i];
        outl[0] = s / (float)NTOK;
    }
}

extern "C" void kernel_launch(void* const* d_in, const int* in_sizes, int n_in,
                              void* d_out, int out_size, void* d_ws, size_t ws_size,
                              hipStream_t stream) {
    const float* vecs = (const float*)d_in[0];   // [B,1,L,D] f32
    const float* mask = (const float*)d_in[1];   // [B,L] f32

    float* out = (float*)d_out;
    float* outq = out + OFF_Q;
    float* outz = out + OFF_Z;
    float* outl = out + OFF_LC;
    float* oute = out + OFF_E;

    // ws layout (f32 offsets): cb 32768 | cc 512 | cbh 16384 | cbl 16384 | partial
    float* ws_f = (float*)d_ws;
    float* cb = ws_f;
    float* cc = ws_f + 32768;
    u16*  cbh = (u16*)(ws_f + 33280);
    u16*  cbl = (u16*)(ws_f + 49664);
    float* partial = ws_f + 66048;

    cb_kernel<<<NS, 64, 0, stream>>>(cb, cc, cbh, cbl);
    fused_kernel<<<NBLK, TPB, 0, stream>>>(vecs, mask, cb, cc, cbh, cbl,
                                           outq, outz, oute, partial);
    fin_kernel<<<1, 512, 0, stream>>>(partial, outl);
}

// Round 15
// 68.276 us; speedup vs baseline: 1.7023x; 1.7023x over previous
//
#include <hip/hip_runtime.h>
#include <math.h>

// SimpleVQ: B=32, H=1, L=4096, D=64, S=512
#define NB 32
#define NL 4096
#define ND 64
#define NS 512
#define NTOK (NB*NL)          // 131072

// output layout (flat f32, return order)
#define OFF_Q 0
#define OFF_Z (NTOK*ND)
#define OFF_LC (OFF_Z + NTOK)
#define OFF_E (OFF_LC + 1)

typedef __attribute__((ext_vector_type(8))) short short8;
typedef __attribute__((ext_vector_type(4))) float f32x4;
typedef unsigned int u32;
typedef unsigned short u16;
typedef unsigned long long u64;

#define QCODES 128            // codes per staged quarter
#define TOKS 128              // tokens per block
#define TPB 512               // 8 waves
#define SLOTS 12              // candidate slots per token
#define SLOTP 13              // padded stride (odd -> conflict-free scans)
#define EPS_H 1e-3f           // >= 2x 3-pass bf16-split h-error bound
#define NBLK (NTOK / TOKS)    // 1024 blocks

// round-to-nearest-even f32 -> bf16 bits
__device__ __forceinline__ u32 f2bf_rne(float x) {
    u32 u = __float_as_uint(x);
    return (u + 0x7fffu + ((u >> 16) & 1u)) >> 16;
}

__device__ __forceinline__ void upd_key(u64& best, float dist, int code) {
    u32 u = __float_as_uint(dist);
    u ^= (u >> 31) ? 0xFFFFFFFFu : 0x80000000u;   // monotone f32 -> u32
    u64 k = ((u64)u << 32) | (u32)code;
    if (k < best) best = k;
}

// ---------------------------------------------------------------------------
// Kernel 1: codebook. cb f32 (linear), cc f32, PRE-SWIZZLED bf16 hi/lo
// (granule g stored at g ^ (code&7)) so a linear LDS copy is conflict-free.
// ---------------------------------------------------------------------------
__global__ void cb_kernel(float* __restrict__ cb, float* __restrict__ cc,
                          u16* __restrict__ cbh, u16* __restrict__ cbl) {
    int s = blockIdx.x;        // 0..511
    int d = threadIdx.x;       // 0..63
    int j = (d < 32) ? d : (d - 32);
    double e = -(double)(2 * j) / 64.0;
    double invlam = pow(100000.0, e);
    double pre = (double)s * invlam;
    float val = (float)((d < 32) ? sin(pre) : cos(pre));

    float sq = val * val;
    #pragma unroll
    for (int off = 32; off > 0; off >>= 1) sq += __shfl_xor(sq, off);
    float mean = sq * (1.0f / 64.0f);
    float scale = (1.0f / sqrtf(mean + 1e-6f)) * 0.35355339059327379f;
    float c = val * scale;
    cb[s * ND + d] = c;

    float c2 = c * c;
    #pragma unroll
    for (int off = 32; off > 0; off >>= 1) c2 += __shfl_xor(c2, off);
    if (d == 0) cc[s] = c2;

    u32 hb = f2bf_rne(c);
    float hf = __uint_as_float(hb << 16);
    u32 lb = f2bf_rne(c - hf);
    int g = d >> 3, ee = d & 7;
    int pos = s * 64 + (((g ^ (s & 7)) << 3) | ee);
    cbh[pos] = (u16)hb;
    cbl[pos] = (u16)lb;
}

// ---------------------------------------------------------------------------
// Kernel 2 (FUSED): per block: 128 tokens, 8 waves, ~78 KB LDS -> 2 blocks/CU.
//  P0: stage vecs f32 -> LDS (XOR-swizzled), convert B-frags once.
//  P1: loop 4 quarters: stage bf16 hi/lo quarter -> MFMA (h = dot - cc/2)
//      -> per-chunk max + eps-rescan -> candidates (code, h) in LDS.
//  P2: global-h filter + exact f32 rescore (identical dist chain),
//      packed-key min (first-min tie rule), 4 threads/token.
//  P3: z / errs2 / partial / coalesced quantized gather-write.
// ---------------------------------------------------------------------------
__launch_bounds__(TPB, 4)
__global__ void fused_kernel(const float* __restrict__ vecs,
                             const float* __restrict__ mask,
                             const float* __restrict__ cb,
                             const float* __restrict__ cc,
                             const u16* __restrict__ cbh,
                             const u16* __restrict__ cbl,
                             float* __restrict__ outq,
                             float* __restrict__ outz,
                             float* __restrict__ oute,
                             float* __restrict__ partial) {
    __shared__ float4 svec[TOKS * 16];          // 32 KB, swizzled f4: g ^ (row&15)
    __shared__ u16 ldsH[QCODES * 64];           // 16 KB
    __shared__ u16 ldsL[QCODES * 64];           // 16 KB
    __shared__ u32 slots[TOKS * SLOTP];         // 6.5 KB
    __shared__ float hval[TOKS * SLOTP];        // 6.5 KB
    __shared__ u32 cnt_l[TOKS];                 // 0.5 KB
    __shared__ int z_l[TOKS];                   // 0.5 KB
    __shared__ float wsum[TPB / 64];

    const int tid = threadIdx.x;
    const int grp = blockIdx.x;      // 0..1023
    const int w = tid >> 6;          // wave 0..7
    const int lane = tid & 63;
    const int c16 = lane & 15;
    const int h = lane >> 4;

    // ---- P0a: stage vecs -> LDS (swizzled), coalesced ----
    {
        const float4* vsrc = (const float4*)(vecs + (size_t)grp * TOKS * ND);
        #pragma unroll
        for (int i = 0; i < 4; ++i) {
            int idx = i * TPB + tid;            // 2048 f4
            int row = idx >> 4, g = idx & 15;
            svec[row * 16 + (g ^ (row & 15))] = vsrc[idx];
        }
        if (tid < TOKS) cnt_l[tid] = 0;
    }
    // stage quarter 0 (1024 short8 per array / 512 threads)
    #pragma unroll
    for (int i = 0; i < 2; ++i) {
        int k = i * TPB + tid;
        ((short8*)ldsH)[k] = ((const short8*)cbh)[k];
        ((short8*)ldsL)[k] = ((const short8*)cbl)[k];
    }
    __syncthreads();

    // ---- P0b: B fragments (once). B[k][col]: col=c16 (token), k=kk*32+h*8+e ----
    const int trow = w * 16 + c16;   // this lane's token 0..127
    short8 bh[2], bl[2];
    #pragma unroll
    for (int kk = 0; kk < 2; ++kk) {
        float x[8];
        #pragma unroll
        for (int u = 0; u < 2; ++u) {
            int g = kk * 8 + h * 2 + u;
            float4 t = svec[trow * 16 + (g ^ (trow & 15))];
            x[u * 4 + 0] = t.x; x[u * 4 + 1] = t.y;
            x[u * 4 + 2] = t.z; x[u * 4 + 3] = t.w;
        }
        short8 H, L;
        #pragma unroll
        for (int e2 = 0; e2 < 8; ++e2) {
            u32 hb = f2bf_rne(x[e2]);
            float hf = __uint_as_float(hb << 16);
            u32 lb = f2bf_rne(x[e2] - hf);
            H[e2] = (short)hb; L[e2] = (short)lb;
        }
        bh[kk] = H; bl[kk] = L;
    }

    // ---- P1: quarters ----
    for (int q = 0; q < 4; ++q) {
        if (q) {
            __syncthreads();   // previous MFMA done with ldsH/L
            #pragma unroll
            for (int i = 0; i < 2; ++i) {
                int k = i * TPB + tid;
                ((short8*)ldsH)[k] = ((const short8*)(cbh + q * QCODES * 64))[k];
                ((short8*)ldsL)[k] = ((const short8*)(cbl + q * QCODES * 64))[k];
            }
            __syncthreads();
        }
        #pragma unroll
        for (int c = 0; c < 2; ++c) {             // two 64-code chunks
            f32x4 acc[4];
            #pragma unroll
            for (int mt = 0; mt < 4; ++mt) {
                int cr = q * QCODES + c * 64 + mt * 16 + h * 4;
                f32x4 ini;
                ini[0] = -0.5f * cc[cr + 0];
                ini[1] = -0.5f * cc[cr + 1];
                ini[2] = -0.5f * cc[cr + 2];
                ini[3] = -0.5f * cc[cr + 3];
                acc[mt] = ini;
            }
            #pragma unroll
            for (int mt = 0; mt < 4; ++mt) {
                int code_l = c * 64 + mt * 16 + c16;
                int sw = code_l & 7;
                short8 ah[2], al[2];
                #pragma unroll
                for (int kk = 0; kk < 2; ++kk) {
                    int off = code_l * 64 + (((kk * 4 + h) ^ sw) << 3);
                    ah[kk] = *(const short8*)(ldsH + off);
                    al[kk] = *(const short8*)(ldsL + off);
                }
                #pragma unroll
                for (int kk = 0; kk < 2; ++kk) {
                    acc[mt] = __builtin_amdgcn_mfma_f32_16x16x32_bf16(ah[kk], bh[kk], acc[mt], 0, 0, 0);
                    acc[mt] = __builtin_amdgcn_mfma_f32_16x16x32_bf16(ah[kk], bl[kk], acc[mt], 0, 0, 0);
                    acc[mt] = __builtin_amdgcn_mfma_f32_16x16x32_bf16(al[kk], bh[kk], acc[mt], 0, 0, 0);
                }
            }
            // epilogue: chunk-max per token, eps-rescan -> candidate append
            float m = acc[0][0];
            #pragma unroll
            for (int mt = 0; mt < 4; ++mt) {
                m = fmaxf(m, fmaxf(fmaxf(acc[mt][0], acc[mt][1]),
                                   fmaxf(acc[mt][2], acc[mt][3])));
            }
            m = fmaxf(m, __shfl_xor(m, 16));
            m = fmaxf(m, __shfl_xor(m, 32));
            float thr = m - EPS_H;
            #pragma unroll
            for (int mt = 0; mt < 4; ++mt) {
                #pragma unroll
                for (int r = 0; r < 4; ++r) {
                    float v = acc[mt][r];
                    if (v >= thr) {
                        u32 pos = atomicAdd(&cnt_l[trow], 1u);
                        if (pos < (u32)SLOTS) {
                            slots[trow * SLOTP + pos] = (u32)(q * QCODES + c * 64 + mt * 16 + h * 4 + r);
                            hval[trow * SLOTP + pos] = v;
                        }
                    }
                }
            }
        }
    }
    __syncthreads();

    // ---- P2: exact rescore, 4 threads/token ----
    const int p  = tid >> 2;          // token-local 0..127
    const int qs = tid & 3;
    const int tok = grp * TOKS + p;

    float4 vf[16];
    #pragma unroll
    for (int g = 0; g < 16; ++g) vf[g] = svec[p * 16 + (g ^ (p & 15))];
    float vv;
    {
        float a0 = 0.f, a1 = 0.f, a2 = 0.f, a3 = 0.f;
        #pragma unroll
        for (int i = 0; i < 16; ++i) {
            a0 = fmaf(vf[i].x, vf[i].x, a0);
            a1 = fmaf(vf[i].y, vf[i].y, a1);
            a2 = fmaf(vf[i].z, vf[i].z, a2);
            a3 = fmaf(vf[i].w, vf[i].w, a3);
        }
        vv = (a0 + a1) + (a2 + a3);
    }

    u32 cnt = cnt_l[p]; if (cnt > (u32)SLOTS) cnt = (u32)SLOTS;
    float hm = -3.4e38f;
    for (u32 j2 = 0; j2 < cnt; ++j2) hm = fmaxf(hm, hval[p * SLOTP + j2]);
    float thr2 = hm - EPS_H;

    u64 best = 0xFFFFFFFFFFFFFFFFull;
    for (u32 j2 = qs; j2 < cnt; j2 += 4) {
        if (hval[p * SLOTP + j2] >= thr2) {
            int code = (int)slots[p * SLOTP + j2];
            const float4* cs = (const float4*)(cb + (size_t)code * ND);
            float d0 = 0.f, d1 = 0.f, d2 = 0.f, d3 = 0.f;
            #pragma unroll
            for (int i2 = 0; i2 < 16; ++i2) {
                float4 cv = cs[i2];
                d0 = fmaf(cv.x, vf[i2].x, d0);
                d1 = fmaf(cv.y, vf[i2].y, d1);
                d2 = fmaf(cv.z, vf[i2].z, d2);
                d3 = fmaf(cv.w, vf[i2].w, d3);
            }
            float dot = (d0 + d1) + (d2 + d3);
            float dist = (vv - 2.0f * dot) + cc[code];
            upd_key(best, dist, code);
        }
    }
    {
        u64 o = __shfl_xor(best, 1); if (o < best) best = o;
        o = __shfl_xor(best, 2); if (o < best) best = o;
    }

    float contrib = 0.0f;
    if (qs == 0) {
        int zi = (int)(best & 0xFFFFFFFFu);
        u32 du = (u32)(best >> 32);
        du ^= (du >> 31) ? 0x80000000u : 0xFFFFFFFFu;
        float dmin = __uint_as_float(du);
        float err = fmaxf(dmin, 0.0f);
        outz[tok] = (float)zi;
        oute[tok] = err;
        z_l[p] = zi;
        contrib = mask[tok] * err;
    }
    #pragma unroll
    for (int off = 32; off > 0; off >>= 1) contrib += __shfl_xor(contrib, off);
    if (lane == 0) wsum[w] = contrib;
    __syncthreads();
    if (tid == 0) {
        float t = 0.f;
        #pragma unroll
        for (int i = 0; i < TPB / 64; ++i) t += wsum[i];
        partial[grp] = t;
    }

    // ---- P3: coalesced quantized gather-write ----
    const float4* cb4 = (const float4*)cb;
    float4* qo = (float4*)(outq + (size_t)grp * TOKS * ND);
    #pragma unroll
    for (int i = 0; i < 4; ++i) {
        int gidx = i * TPB + tid;      // 2048 f4
        int t2 = gidx >> 4;
        int sub = gidx & 15;
        qo[gidx] = cb4[(size_t)z_l[t2] * 16 + sub];
    }
}

// ---------------------------------------------------------------------------
// Kernel 3: sum 1024 partials; l_commit = sum / (B*L)
// ---------------------------------------------------------------------------
__global__ void fin_kernel(const float* __restrict__ partial, float* __restrict__ outl) {
    int t = threadIdx.x;                 // 1024
    float x = partial[t];
    #pragma unroll
    for (int off = 32; off > 0; off >>= 1) x += __shfl_xor(x, off);
    __shared__ float ws[16];
    if ((t & 63) == 0) ws[t >> 6] = x;
    __syncthreads();
    if (t == 0) {
        float s = 0.f;
        #pragma unroll
        for (int i = 0; i < 16; ++i) s += ws[i];
        outl[0] = s / (float)NTOK;
    }
}

extern "C" void kernel_launch(void* const* d_in, const int* in_sizes, int n_in,
                              void* d_out, int out_size, void* d_ws, size_t ws_size,
                              hipStream_t stream) {
    const float* vecs = (const float*)d_in[0];   // [B,1,L,D] f32
    const float* mask = (const float*)d_in[1];   // [B,L] f32

    float* out = (float*)d_out;
    float* outq = out + OFF_Q;
    float* outz = out + OFF_Z;
    float* outl = out + OFF_LC;
    float* oute = out + OFF_E;

    // ws layout (f32 offsets): cb 32768 | cc 512 | cbh 16384 | cbl 16384 | partial
    float* ws_f = (float*)d_ws;
    float* cb = ws_f;
    float* cc = ws_f + 32768;
    u16*  cbh = (u16*)(ws_f + 33280);
    u16*  cbl = (u16*)(ws_f + 49664);
    float* partial = ws_f + 66048;

    cb_kernel<<<NS, 64, 0, stream>>>(cb, cc, cbh, cbl);
    fused_kernel<<<NBLK, TPB, 0, stream>>>(vecs, mask, cb, cc, cbh, cbl,
                                           outq, outz, oute, partial);
    fin_kernel<<<1, 1024, 0, stream>>>(partial, outl);
}

// Round 16
// 68.129 us; speedup vs baseline: 1.7060x; 1.0022x over previous
//
#include <hip/hip_runtime.h>
#include <math.h>

// SimpleVQ: B=32, H=1, L=4096, D=64, S=512
#define NB 32
#define NL 4096
#define ND 64
#define NS 512
#define NTOK (NB*NL)          // 131072

// output layout (flat f32, return order)
#define OFF_Q 0
#define OFF_Z (NTOK*ND)
#define OFF_LC (OFF_Z + NTOK)
#define OFF_E (OFF_LC + 1)

typedef __attribute__((ext_vector_type(8))) short short8;
typedef __attribute__((ext_vector_type(4))) float f32x4;
typedef unsigned int u32;
typedef unsigned short u16;
typedef unsigned long long u64;

#define QCODES 128            // codes per staged quarter
#define TOKS 128              // tokens per block
#define TPB 512               // 8 waves
#define SLOTS 12              // candidate slots per token
#define SLOTP 13              // padded stride (odd -> conflict-free scans)
#define EPS_H 1e-3f           // >= 2x 3-pass bf16-split h-error bound
#define NBLK (NTOK / TOKS)    // 1024 blocks

// round-to-nearest-even f32 -> bf16 bits
__device__ __forceinline__ u32 f2bf_rne(float x) {
    u32 u = __float_as_uint(x);
    return (u + 0x7fffu + ((u >> 16) & 1u)) >> 16;
}

__device__ __forceinline__ void upd_key(u64& best, float dist, int code) {
    u32 u = __float_as_uint(dist);
    u ^= (u >> 31) ? 0xFFFFFFFFu : 0x80000000u;   // monotone f32 -> u32
    u64 k = ((u64)u << 32) | (u32)code;
    if (k < best) best = k;
}

// ---------------------------------------------------------------------------
// Kernel 1: codebook. cb f32 (linear), cc f32, PRE-SWIZZLED bf16 hi/lo
// (granule g stored at g ^ (code&7)) so a linear LDS copy is conflict-free.
// ---------------------------------------------------------------------------
__global__ void cb_kernel(float* __restrict__ cb, float* __restrict__ cc,
                          u16* __restrict__ cbh, u16* __restrict__ cbl) {
    int s = blockIdx.x;        // 0..511
    int d = threadIdx.x;       // 0..63
    int j = (d < 32) ? d : (d - 32);
    double e = -(double)(2 * j) / 64.0;
    double invlam = pow(100000.0, e);
    double pre = (double)s * invlam;
    float val = (float)((d < 32) ? sin(pre) : cos(pre));

    float sq = val * val;
    #pragma unroll
    for (int off = 32; off > 0; off >>= 1) sq += __shfl_xor(sq, off);
    float mean = sq * (1.0f / 64.0f);
    float scale = (1.0f / sqrtf(mean + 1e-6f)) * 0.35355339059327379f;
    float c = val * scale;
    cb[s * ND + d] = c;

    float c2 = c * c;
    #pragma unroll
    for (int off = 32; off > 0; off >>= 1) c2 += __shfl_xor(c2, off);
    if (d == 0) cc[s] = c2;

    u32 hb = f2bf_rne(c);
    float hf = __uint_as_float(hb << 16);
    u32 lb = f2bf_rne(c - hf);
    int g = d >> 3, ee = d & 7;
    int pos = s * 64 + (((g ^ (s & 7)) << 3) | ee);
    cbh[pos] = (u16)hb;
    cbl[pos] = (u16)lb;
}

// ---------------------------------------------------------------------------
// Kernel 2 (FUSED): per block: 128 tokens, 8 waves, ~78 KB LDS -> 2 blocks/CU.
// r15 structure with two cuts:
//  - quarter re-stage: global loads PREFETCHED into regs before the MFMA of
//    the previous quarter; barrier pair now sandwiches only the ds_writes.
//  - barrier between P1 and P2 removed (candidate lists are wave-local:
//    wave w writes tokens [w*16,(w+1)*16) and rescores exactly those).
// ---------------------------------------------------------------------------
__launch_bounds__(TPB, 3)
__global__ void fused_kernel(const float* __restrict__ vecs,
                             const float* __restrict__ mask,
                             const float* __restrict__ cb,
                             const float* __restrict__ cc,
                             const u16* __restrict__ cbh,
                             const u16* __restrict__ cbl,
                             float* __restrict__ outq,
                             float* __restrict__ outz,
                             float* __restrict__ oute,
                             float* __restrict__ partial) {
    __shared__ float4 svec[TOKS * 16];          // 32 KB, swizzled f4: g ^ (row&15)
    __shared__ u16 ldsH[QCODES * 64];           // 16 KB
    __shared__ u16 ldsL[QCODES * 64];           // 16 KB
    __shared__ u32 slots[TOKS * SLOTP];         // 6.5 KB
    __shared__ float hval[TOKS * SLOTP];        // 6.5 KB
    __shared__ u32 cnt_l[TOKS];                 // 0.5 KB
    __shared__ int z_l[TOKS];                   // 0.5 KB
    __shared__ float wsum[TPB / 64];

    const int tid = threadIdx.x;
    const int grp = blockIdx.x;      // 0..1023
    const int w = tid >> 6;          // wave 0..7
    const int lane = tid & 63;
    const int c16 = lane & 15;
    const int h = lane >> 4;

    // ---- P0a: stage vecs -> LDS (swizzled), coalesced ----
    {
        const float4* vsrc = (const float4*)(vecs + (size_t)grp * TOKS * ND);
        #pragma unroll
        for (int i = 0; i < 4; ++i) {
            int idx = i * TPB + tid;            // 2048 f4
            int row = idx >> 4, g = idx & 15;
            svec[row * 16 + (g ^ (row & 15))] = vsrc[idx];
        }
        if (tid < TOKS) cnt_l[tid] = 0;
    }
    // stage quarter 0 (1024 short8 per array / 512 threads)
    #pragma unroll
    for (int i = 0; i < 2; ++i) {
        int k = i * TPB + tid;
        ((short8*)ldsH)[k] = ((const short8*)cbh)[k];
        ((short8*)ldsL)[k] = ((const short8*)cbl)[k];
    }
    __syncthreads();                 // barrier #1

    // ---- P0b: B fragments (once). B[k][col]: col=c16 (token), k=kk*32+h*8+e ----
    const int trow = w * 16 + c16;   // this lane's token 0..127
    short8 bh[2], bl[2];
    #pragma unroll
    for (int kk = 0; kk < 2; ++kk) {
        float x[8];
        #pragma unroll
        for (int u = 0; u < 2; ++u) {
            int g = kk * 8 + h * 2 + u;
            float4 t = svec[trow * 16 + (g ^ (trow & 15))];
            x[u * 4 + 0] = t.x; x[u * 4 + 1] = t.y;
            x[u * 4 + 2] = t.z; x[u * 4 + 3] = t.w;
        }
        short8 H, L;
        #pragma unroll
        for (int e2 = 0; e2 < 8; ++e2) {
            u32 hb = f2bf_rne(x[e2]);
            float hf = __uint_as_float(hb << 16);
            u32 lb = f2bf_rne(x[e2] - hf);
            H[e2] = (short)hb; L[e2] = (short)lb;
        }
        bh[kk] = H; bl[kk] = L;
    }

    // ---- P1: quarters, register-prefetched staging ----
    for (int q = 0; q < 4; ++q) {
        // prefetch next quarter into regs; latency hides under this quarter's MFMA
        short8 gh[2], gl[2];
        if (q < 3) {
            const short8* sH = (const short8*)(cbh + (q + 1) * QCODES * 64);
            const short8* sL = (const short8*)(cbl + (q + 1) * QCODES * 64);
            #pragma unroll
            for (int i = 0; i < 2; ++i) {
                gh[i] = sH[i * TPB + tid];
                gl[i] = sL[i * TPB + tid];
            }
        }

        #pragma unroll
        for (int c = 0; c < 2; ++c) {             // two 64-code chunks
            f32x4 acc[4];
            #pragma unroll
            for (int mt = 0; mt < 4; ++mt) {
                int cr = q * QCODES + c * 64 + mt * 16 + h * 4;
                f32x4 ini;
                ini[0] = -0.5f * cc[cr + 0];
                ini[1] = -0.5f * cc[cr + 1];
                ini[2] = -0.5f * cc[cr + 2];
                ini[3] = -0.5f * cc[cr + 3];
                acc[mt] = ini;
            }
            #pragma unroll
            for (int mt = 0; mt < 4; ++mt) {
                int code_l = c * 64 + mt * 16 + c16;
                int sw = code_l & 7;
                short8 ah[2], al[2];
                #pragma unroll
                for (int kk = 0; kk < 2; ++kk) {
                    int off = code_l * 64 + (((kk * 4 + h) ^ sw) << 3);
                    ah[kk] = *(const short8*)(ldsH + off);
                    al[kk] = *(const short8*)(ldsL + off);
                }
                #pragma unroll
                for (int kk = 0; kk < 2; ++kk) {
                    acc[mt] = __builtin_amdgcn_mfma_f32_16x16x32_bf16(ah[kk], bh[kk], acc[mt], 0, 0, 0);
                    acc[mt] = __builtin_amdgcn_mfma_f32_16x16x32_bf16(ah[kk], bl[kk], acc[mt], 0, 0, 0);
                    acc[mt] = __builtin_amdgcn_mfma_f32_16x16x32_bf16(al[kk], bh[kk], acc[mt], 0, 0, 0);
                }
            }
            // epilogue: chunk-max per token, eps-rescan -> candidate append
            float m = acc[0][0];
            #pragma unroll
            for (int mt = 0; mt < 4; ++mt) {
                m = fmaxf(m, fmaxf(fmaxf(acc[mt][0], acc[mt][1]),
                                   fmaxf(acc[mt][2], acc[mt][3])));
            }
            m = fmaxf(m, __shfl_xor(m, 16));
            m = fmaxf(m, __shfl_xor(m, 32));
            float thr = m - EPS_H;
            #pragma unroll
            for (int mt = 0; mt < 4; ++mt) {
                #pragma unroll
                for (int r = 0; r < 4; ++r) {
                    float v = acc[mt][r];
                    if (v >= thr) {
                        u32 pos = atomicAdd(&cnt_l[trow], 1u);
                        if (pos < (u32)SLOTS) {
                            slots[trow * SLOTP + pos] = (u32)(q * QCODES + c * 64 + mt * 16 + h * 4 + r);
                            hval[trow * SLOTP + pos] = v;
                        }
                    }
                }
            }
        }

        // swap in the prefetched quarter: barriers sandwich only the ds_writes
        if (q < 3) {
            __syncthreads();          // all waves done reading current quarter
            #pragma unroll
            for (int i = 0; i < 2; ++i) {
                int k = i * TPB + tid;
                ((short8*)ldsH)[k] = gh[i];
                ((short8*)ldsL)[k] = gl[i];
            }
            __syncthreads();          // new quarter visible
        }
    }
    // NO barrier here: wave w wrote candidates only for tokens [w*16,(w+1)*16)
    // and rescans exactly those tokens below (tid>>2 >> 4 == tid>>6 == w).

    // ---- P2: exact rescore, 4 threads/token ----
    const int p  = tid >> 2;          // token-local 0..127
    const int qs = tid & 3;
    const int tok = grp * TOKS + p;

    float4 vf[16];
    #pragma unroll
    for (int g = 0; g < 16; ++g) vf[g] = svec[p * 16 + (g ^ (p & 15))];
    float vv;
    {
        float a0 = 0.f, a1 = 0.f, a2 = 0.f, a3 = 0.f;
        #pragma unroll
        for (int i = 0; i < 16; ++i) {
            a0 = fmaf(vf[i].x, vf[i].x, a0);
            a1 = fmaf(vf[i].y, vf[i].y, a1);
            a2 = fmaf(vf[i].z, vf[i].z, a2);
            a3 = fmaf(vf[i].w, vf[i].w, a3);
        }
        vv = (a0 + a1) + (a2 + a3);
    }

    u32 cnt = cnt_l[p]; if (cnt > (u32)SLOTS) cnt = (u32)SLOTS;
    float hm = -3.4e38f;
    for (u32 j2 = 0; j2 < cnt; ++j2) hm = fmaxf(hm, hval[p * SLOTP + j2]);
    float thr2 = hm - EPS_H;

    u64 best = 0xFFFFFFFFFFFFFFFFull;
    for (u32 j2 = qs; j2 < cnt; j2 += 4) {
        if (hval[p * SLOTP + j2] >= thr2) {
            int code = (int)slots[p * SLOTP + j2];
            const float4* cs = (const float4*)(cb + (size_t)code * ND);
            float d0 = 0.f, d1 = 0.f, d2 = 0.f, d3 = 0.f;
            #pragma unroll
            for (int i2 = 0; i2 < 16; ++i2) {
                float4 cv = cs[i2];
                d0 = fmaf(cv.x, vf[i2].x, d0);
                d1 = fmaf(cv.y, vf[i2].y, d1);
                d2 = fmaf(cv.z, vf[i2].z, d2);
                d3 = fmaf(cv.w, vf[i2].w, d3);
            }
            float dot = (d0 + d1) + (d2 + d3);
            float dist = (vv - 2.0f * dot) + cc[code];
            upd_key(best, dist, code);
        }
    }
    {
        u64 o = __shfl_xor(best, 1); if (o < best) best = o;
        o = __shfl_xor(best, 2); if (o < best) best = o;
    }

    float contrib = 0.0f;
    if (qs == 0) {
        int zi = (int)(best & 0xFFFFFFFFu);
        u32 du = (u32)(best >> 32);
        du ^= (du >> 31) ? 0x80000000u : 0xFFFFFFFFu;
        float dmin = __uint_as_float(du);
        float err = fmaxf(dmin, 0.0f);
        outz[tok] = (float)zi;
        oute[tok] = err;
        z_l[p] = zi;
        contrib = mask[tok] * err;
    }
    #pragma unroll
    for (int off = 32; off > 0; off >>= 1) contrib += __shfl_xor(contrib, off);
    if (lane == 0) wsum[w] = contrib;
    __syncthreads();
    if (tid == 0) {
        float t = 0.f;
        #pragma unroll
        for (int i = 0; i < TPB / 64; ++i) t += wsum[i];
        partial[grp] = t;
    }

    // ---- P3: coalesced quantized gather-write ----
    const float4* cb4 = (const float4*)cb;
    float4* qo = (float4*)(outq + (size_t)grp * TOKS * ND);
    #pragma unroll
    for (int i = 0; i < 4; ++i) {
        int gidx = i * TPB + tid;      // 2048 f4
        int t2 = gidx >> 4;
        int sub = gidx & 15;
        qo[gidx] = cb4[(size_t)z_l[t2] * 16 + sub];
    }
}

// ---------------------------------------------------------------------------
// Kernel 3: sum 1024 partials; l_commit = sum / (B*L)
// ---------------------------------------------------------------------------
__global__ void fin_kernel(const float* __restrict__ partial, float* __restrict__ outl) {
    int t = threadIdx.x;                 // 1024
    float x = partial[t];
    #pragma unroll
    for (int off = 32; off > 0; off >>= 1) x += __shfl_xor(x, off);
    __shared__ float ws[16];
    if ((t & 63) == 0) ws[t >> 6] = x;
    __syncthreads();
    if (t == 0) {
        float s = 0.f;
        #pragma unroll
        for (int i = 0; i < 16; ++i) s += ws[i];
        outl[0] = s / (float)NTOK;
    }
}

extern "C" void kernel_launch(void* const* d_in, const int* in_sizes, int n_in,
                              void* d_out, int out_size, void* d_ws, size_t ws_size,
                              hipStream_t stream) {
    const float* vecs = (const float*)d_in[0];   // [B,1,L,D] f32
    const float* mask = (const float*)d_in[1];   // [B,L] f32

    float* out = (float*)d_out;
    float* outq = out + OFF_Q;
    float* outz = out + OFF_Z;
    float* outl = out + OFF_LC;
    float* oute = out + OFF_E;

    // ws layout (f32 offsets): cb 32768 | cc 512 | cbh 16384 | cbl 16384 | partial
    float* ws_f = (float*)d_ws;
    float* cb = ws_f;
    float* cc = ws_f + 32768;
    u16*  cbh = (u16*)(ws_f + 33280);
    u16*  cbl = (u16*)(ws_f + 49664);
    float* partial = ws_f + 66048;

    cb_kernel<<<NS, 64, 0, stream>>>(cb, cc, cbh, cbl);
    fused_kernel<<<NBLK, TPB, 0, stream>>>(vecs, mask, cb, cc, cbh, cbl,
                                           outq, outz, oute, partial);
    fin_kernel<<<1, 1024, 0, stream>>>(partial, outl);
}

// Round 17
// 65.944 us; speedup vs baseline: 1.7625x; 1.0331x over previous
//
#include <hip/hip_runtime.h>
#include <math.h>

// SimpleVQ: B=32, H=1, L=4096, D=64, S=512
#define NB 32
#define NL 4096
#define ND 64
#define NS 512
#define NTOK (NB*NL)          // 131072

// output layout (flat f32, return order)
#define OFF_Q 0
#define OFF_Z (NTOK*ND)
#define OFF_LC (OFF_Z + NTOK)
#define OFF_E (OFF_LC + 1)

typedef __attribute__((ext_vector_type(8))) short short8;
typedef __attribute__((ext_vector_type(4))) float f32x4;
typedef unsigned int u32;
typedef unsigned short u16;
typedef unsigned long long u64;

#define QCODES 128            // codes per staged quarter
#define TOKS 128              // tokens per block
#define TPB 512               // 8 waves
#define SLOTS 12              // candidate slots per token
#define SLOTP 13              // padded stride (odd -> conflict-free scans)
#define EPS_H 1e-3f           // >= 2x 3-pass bf16-split h-error bound
#define NBLK (NTOK / TOKS)    // 1024 blocks

// round-to-nearest-even f32 -> bf16 bits
__device__ __forceinline__ u32 f2bf_rne(float x) {
    u32 u = __float_as_uint(x);
    return (u + 0x7fffu + ((u >> 16) & 1u)) >> 16;
}

__device__ __forceinline__ void upd_key(u64& best, float dist, int code) {
    u32 u = __float_as_uint(dist);
    u ^= (u >> 31) ? 0xFFFFFFFFu : 0x80000000u;   // monotone f32 -> u32
    u64 k = ((u64)u << 32) | (u32)code;
    if (k < best) best = k;
}

// ---------------------------------------------------------------------------
// Kernel 1: codebook. cb f32 (linear), cc f32, PRE-SWIZZLED bf16 hi/lo
// (granule g stored at g ^ (code&7)) so a linear LDS copy is conflict-free.
// ---------------------------------------------------------------------------
__global__ void cb_kernel(float* __restrict__ cb, float* __restrict__ cc,
                          u16* __restrict__ cbh, u16* __restrict__ cbl) {
    int s = blockIdx.x;        // 0..511
    int d = threadIdx.x;       // 0..63
    int j = (d < 32) ? d : (d - 32);
    double e = -(double)(2 * j) / 64.0;
    double invlam = pow(100000.0, e);
    double pre = (double)s * invlam;
    float val = (float)((d < 32) ? sin(pre) : cos(pre));

    float sq = val * val;
    #pragma unroll
    for (int off = 32; off > 0; off >>= 1) sq += __shfl_xor(sq, off);
    float mean = sq * (1.0f / 64.0f);
    float scale = (1.0f / sqrtf(mean + 1e-6f)) * 0.35355339059327379f;
    float c = val * scale;
    cb[s * ND + d] = c;

    float c2 = c * c;
    #pragma unroll
    for (int off = 32; off > 0; off >>= 1) c2 += __shfl_xor(c2, off);
    if (d == 0) cc[s] = c2;

    u32 hb = f2bf_rne(c);
    float hf = __uint_as_float(hb << 16);
    u32 lb = f2bf_rne(c - hf);
    int g = d >> 3, ee = d & 7;
    int pos = s * 64 + (((g ^ (s & 7)) << 3) | ee);
    cbh[pos] = (u16)hb;
    cbl[pos] = (u16)lb;
}

// ---------------------------------------------------------------------------
// Kernel 2 (FUSED): per block: 128 tokens, 8 waves, ~47 KB LDS -> 3 blocks/CU
// (24 waves/CU). r16 structure minus svec: vecs is L2/L3-resident, so
// B-fragments convert directly from global (r9 pattern) and P2 reads its
// token row directly from global. All selection math byte-identical to r16.
// ---------------------------------------------------------------------------
__launch_bounds__(TPB, 3)
__global__ void fused_kernel(const float* __restrict__ vecs,
                             const float* __restrict__ mask,
                             const float* __restrict__ cb,
                             const float* __restrict__ cc,
                             const u16* __restrict__ cbh,
                             const u16* __restrict__ cbl,
                             float* __restrict__ outq,
                             float* __restrict__ outz,
                             float* __restrict__ oute,
                             float* __restrict__ partial) {
    __shared__ u16 ldsH[QCODES * 64];           // 16 KB
    __shared__ u16 ldsL[QCODES * 64];           // 16 KB
    __shared__ u32 slots[TOKS * SLOTP];         // 6.5 KB
    __shared__ float hval[TOKS * SLOTP];        // 6.5 KB
    __shared__ u32 cnt_l[TOKS];                 // 0.5 KB
    __shared__ int z_l[TOKS];                   // 0.5 KB
    __shared__ float wsum[TPB / 64];

    const int tid = threadIdx.x;
    const int grp = blockIdx.x;      // 0..1023
    const int w = tid >> 6;          // wave 0..7
    const int lane = tid & 63;
    const int c16 = lane & 15;
    const int h = lane >> 4;

    // ---- P0: stage quarter 0 + zero counters ----
    #pragma unroll
    for (int i = 0; i < 2; ++i) {
        int k = i * TPB + tid;       // 1024 short8 per array
        ((short8*)ldsH)[k] = ((const short8*)cbh)[k];
        ((short8*)ldsL)[k] = ((const short8*)cbl)[k];
    }
    if (tid < TOKS) cnt_l[tid] = 0;

    // ---- B fragments direct from global (r9 pattern). ----
    // B[k][col]: col = c16 (token), k = kk*32 + h*8 + e
    const int trow = w * 16 + c16;   // this lane's token 0..127
    short8 bh[2], bl[2];
    {
        const float* vp = vecs + (size_t)(grp * TOKS + trow) * ND;
        #pragma unroll
        for (int kk = 0; kk < 2; ++kk) {
            const float4* pp = (const float4*)(vp + kk * 32 + h * 8);
            float4 t0 = pp[0], t1 = pp[1];
            float x[8] = {t0.x, t0.y, t0.z, t0.w, t1.x, t1.y, t1.z, t1.w};
            short8 H, L;
            #pragma unroll
            for (int e2 = 0; e2 < 8; ++e2) {
                u32 hb = f2bf_rne(x[e2]);
                float hf = __uint_as_float(hb << 16);
                u32 lb = f2bf_rne(x[e2] - hf);
                H[e2] = (short)hb; L[e2] = (short)lb;
            }
            bh[kk] = H; bl[kk] = L;
        }
    }
    __syncthreads();                 // barrier #1: quarter 0 + counters ready

    // ---- P1: quarters, register-prefetched staging ----
    for (int q = 0; q < 4; ++q) {
        // prefetch next quarter into regs; latency hides under this quarter's MFMA
        short8 gh[2], gl[2];
        if (q < 3) {
            const short8* sH = (const short8*)(cbh + (q + 1) * QCODES * 64);
            const short8* sL = (const short8*)(cbl + (q + 1) * QCODES * 64);
            #pragma unroll
            for (int i = 0; i < 2; ++i) {
                gh[i] = sH[i * TPB + tid];
                gl[i] = sL[i * TPB + tid];
            }
        }

        #pragma unroll
        for (int c = 0; c < 2; ++c) {             // two 64-code chunks
            f32x4 acc[4];
            #pragma unroll
            for (int mt = 0; mt < 4; ++mt) {
                int cr = q * QCODES + c * 64 + mt * 16 + h * 4;
                f32x4 ini;
                ini[0] = -0.5f * cc[cr + 0];
                ini[1] = -0.5f * cc[cr + 1];
                ini[2] = -0.5f * cc[cr + 2];
                ini[3] = -0.5f * cc[cr + 3];
                acc[mt] = ini;
            }
            #pragma unroll
            for (int mt = 0; mt < 4; ++mt) {
                int code_l = c * 64 + mt * 16 + c16;
                int sw = code_l & 7;
                short8 ah[2], al[2];
                #pragma unroll
                for (int kk = 0; kk < 2; ++kk) {
                    int off = code_l * 64 + (((kk * 4 + h) ^ sw) << 3);
                    ah[kk] = *(const short8*)(ldsH + off);
                    al[kk] = *(const short8*)(ldsL + off);
                }
                #pragma unroll
                for (int kk = 0; kk < 2; ++kk) {
                    acc[mt] = __builtin_amdgcn_mfma_f32_16x16x32_bf16(ah[kk], bh[kk], acc[mt], 0, 0, 0);
                    acc[mt] = __builtin_amdgcn_mfma_f32_16x16x32_bf16(ah[kk], bl[kk], acc[mt], 0, 0, 0);
                    acc[mt] = __builtin_amdgcn_mfma_f32_16x16x32_bf16(al[kk], bh[kk], acc[mt], 0, 0, 0);
                }
            }
            // epilogue: chunk-max per token, eps-rescan -> candidate append
            float m = acc[0][0];
            #pragma unroll
            for (int mt = 0; mt < 4; ++mt) {
                m = fmaxf(m, fmaxf(fmaxf(acc[mt][0], acc[mt][1]),
                                   fmaxf(acc[mt][2], acc[mt][3])));
            }
            m = fmaxf(m, __shfl_xor(m, 16));
            m = fmaxf(m, __shfl_xor(m, 32));
            float thr = m - EPS_H;
            #pragma unroll
            for (int mt = 0; mt < 4; ++mt) {
                #pragma unroll
                for (int r = 0; r < 4; ++r) {
                    float v = acc[mt][r];
                    if (v >= thr) {
                        u32 pos = atomicAdd(&cnt_l[trow], 1u);
                        if (pos < (u32)SLOTS) {
                            slots[trow * SLOTP + pos] = (u32)(q * QCODES + c * 64 + mt * 16 + h * 4 + r);
                            hval[trow * SLOTP + pos] = v;
                        }
                    }
                }
            }
        }

        // swap in the prefetched quarter: barriers sandwich only the ds_writes
        if (q < 3) {
            __syncthreads();          // all waves done reading current quarter
            #pragma unroll
            for (int i = 0; i < 2; ++i) {
                int k = i * TPB + tid;
                ((short8*)ldsH)[k] = gh[i];
                ((short8*)ldsL)[k] = gl[i];
            }
            __syncthreads();          // new quarter visible
        }
    }
    // NO barrier here: wave w wrote candidates only for tokens [w*16,(w+1)*16)
    // and rescans exactly those tokens below (tid>>2 >> 4 == tid>>6 == w).

    // ---- P2: exact rescore, 4 threads/token; vf direct from global ----
    const int p  = tid >> 2;          // token-local 0..127
    const int qs = tid & 3;
    const int tok = grp * TOKS + p;

    float4 vf[16];
    {
        const float4* vr = (const float4*)(vecs + (size_t)tok * ND);
        #pragma unroll
        for (int g = 0; g < 16; ++g) vf[g] = vr[g];
    }
    float vv;
    {
        float a0 = 0.f, a1 = 0.f, a2 = 0.f, a3 = 0.f;
        #pragma unroll
        for (int i = 0; i < 16; ++i) {
            a0 = fmaf(vf[i].x, vf[i].x, a0);
            a1 = fmaf(vf[i].y, vf[i].y, a1);
            a2 = fmaf(vf[i].z, vf[i].z, a2);
            a3 = fmaf(vf[i].w, vf[i].w, a3);
        }
        vv = (a0 + a1) + (a2 + a3);
    }

    u32 cnt = cnt_l[p]; if (cnt > (u32)SLOTS) cnt = (u32)SLOTS;
    float hm = -3.4e38f;
    for (u32 j2 = 0; j2 < cnt; ++j2) hm = fmaxf(hm, hval[p * SLOTP + j2]);
    float thr2 = hm - EPS_H;

    u64 best = 0xFFFFFFFFFFFFFFFFull;
    for (u32 j2 = qs; j2 < cnt; j2 += 4) {
        if (hval[p * SLOTP + j2] >= thr2) {
            int code = (int)slots[p * SLOTP + j2];
            const float4* cs = (const float4*)(cb + (size_t)code * ND);
            float d0 = 0.f, d1 = 0.f, d2 = 0.f, d3 = 0.f;
            #pragma unroll
            for (int i2 = 0; i2 < 16; ++i2) {
                float4 cv = cs[i2];
                d0 = fmaf(cv.x, vf[i2].x, d0);
                d1 = fmaf(cv.y, vf[i2].y, d1);
                d2 = fmaf(cv.z, vf[i2].z, d2);
                d3 = fmaf(cv.w, vf[i2].w, d3);
            }
            float dot = (d0 + d1) + (d2 + d3);
            float dist = (vv - 2.0f * dot) + cc[code];
            upd_key(best, dist, code);
        }
    }
    {
        u64 o = __shfl_xor(best, 1); if (o < best) best = o;
        o = __shfl_xor(best, 2); if (o < best) best = o;
    }

    float contrib = 0.0f;
    if (qs == 0) {
        int zi = (int)(best & 0xFFFFFFFFu);
        u32 du = (u32)(best >> 32);
        du ^= (du >> 31) ? 0x80000000u : 0xFFFFFFFFu;
        float dmin = __uint_as_float(du);
        float err = fmaxf(dmin, 0.0f);
        outz[tok] = (float)zi;
        oute[tok] = err;
        z_l[p] = zi;
        contrib = mask[tok] * err;
    }
    #pragma unroll
    for (int off = 32; off > 0; off >>= 1) contrib += __shfl_xor(contrib, off);
    if (lane == 0) wsum[w] = contrib;
    __syncthreads();
    if (tid == 0) {
        float t = 0.f;
        #pragma unroll
        for (int i = 0; i < TPB / 64; ++i) t += wsum[i];
        partial[grp] = t;
    }

    // ---- P3: coalesced quantized gather-write ----
    const float4* cb4 = (const float4*)cb;
    float4* qo = (float4*)(outq + (size_t)grp * TOKS * ND);
    #pragma unroll
    for (int i = 0; i < 4; ++i) {
        int gidx = i * TPB + tid;      // 2048 f4
        int t2 = gidx >> 4;
        int sub = gidx & 15;
        qo[gidx] = cb4[(size_t)z_l[t2] * 16 + sub];
    }
}

// ---------------------------------------------------------------------------
// Kernel 3: sum 1024 partials; l_commit = sum / (B*L)
// ---------------------------------------------------------------------------
__global__ void fin_kernel(const float* __restrict__ partial, float* __restrict__ outl) {
    int t = threadIdx.x;                 // 1024
    float x = partial[t];
    #pragma unroll
    for (int off = 32; off > 0; off >>= 1) x += __shfl_xor(x, off);
    __shared__ float ws[16];
    if ((t & 63) == 0) ws[t >> 6] = x;
    __syncthreads();
    if (t == 0) {
        float s = 0.f;
        #pragma unroll
        for (int i = 0; i < 16; ++i) s += ws[i];
        outl[0] = s / (float)NTOK;
    }
}

extern "C" void kernel_launch(void* const* d_in, const int* in_sizes, int n_in,
                              void* d_out, int out_size, void* d_ws, size_t ws_size,
                              hipStream_t stream) {
    const float* vecs = (const float*)d_in[0];   // [B,1,L,D] f32
    const float* mask = (const float*)d_in[1];   // [B,L] f32

    float* out = (float*)d_out;
    float* outq = out + OFF_Q;
    float* outz = out + OFF_Z;
    float* outl = out + OFF_LC;
    float* oute = out + OFF_E;

    // ws layout (f32 offsets): cb 32768 | cc 512 | cbh 16384 | cbl 16384 | partial
    float* ws_f = (float*)d_ws;
    float* cb = ws_f;
    float* cc = ws_f + 32768;
    u16*  cbh = (u16*)(ws_f + 33280);
    u16*  cbl = (u16*)(ws_f + 49664);
    float* partial = ws_f + 66048;

    cb_kernel<<<NS, 64, 0, stream>>>(cb, cc, cbh, cbl);
    fused_kernel<<<NBLK, TPB, 0, stream>>>(vecs, mask, cb, cc, cbh, cbl,
                                           outq, outz, oute, partial);
    fin_kernel<<<1, 1024, 0, stream>>>(partial, outl);
}